// Round 10
// baseline (228.930 us; speedup 1.0000x reference)
//
#include <hip/hip_runtime.h>
#include <math.h>

#define HOP     128
#define NSLOTS  256
#define FPW     4      // frames per wave-chain: 8192 chains / 2048 blocks = full residency
#define PI_F    3.14159265358979323846f
#define PI2_F   1.57079632679489661923f
#define K8      0.70710678118654752440f

// Zero-instruction ordering fence for intra-wave LDS cross-lane handoffs.
#define LDS_FENCE() do { __asm__ volatile("" ::: "memory"); \
                         __builtin_amdgcn_wave_barrier(); } while (0)

struct cpx { float x, y; };
__device__ __forceinline__ cpx cadd(cpx a, cpx b){ return {a.x+b.x, a.y+b.y}; }
__device__ __forceinline__ cpx csub(cpx a, cpx b){ return {a.x-b.x, a.y-b.y}; }
__device__ __forceinline__ cpx cmul(cpx a, cpx b){
    return {fmaf(a.x,b.x,-a.y*b.y), fmaf(a.x,b.y, a.y*b.x)};
}
__device__ __forceinline__ cpx cmulc(cpx a, cpx b){  // a*conj(b)
    return {fmaf(a.x,b.x, a.y*b.y), fmaf(a.y,b.x,-a.x*b.y)};
}

// |atan2(im,re)| in [0,pi]
__device__ __forceinline__ float abs_angle(float re, float im) {
    float a = fabsf(im), b = fabsf(re);
    float mn = fminf(a, b), mx = fmaxf(a, b);
    float t = __fdividef(mn, fmaxf(mx, 1e-37f));
    float t2 = t * t;
    float p = fmaf(t2, -0.0117212f, 0.05265332f);
    p = fmaf(t2, p, -0.11643287f);
    p = fmaf(t2, p, 0.19354346f);
    p = fmaf(t2, p, -0.33262347f);
    p = fmaf(t2, p, 0.99997726f);
    float r = t * p;
    r = (a > b) ? (PI2_F - r) : r;
    r = (re < 0.f) ? (PI_F - r) : r;
    return r;
}

// In-register 8-point DFT, natural-order output.
__device__ __forceinline__ void dft8(cpx v[8]) {
    cpx a0=cadd(v[0],v[4]), a1=cadd(v[1],v[5]), a2=cadd(v[2],v[6]), a3=cadd(v[3],v[7]);
    cpx b0=csub(v[0],v[4]), b1=csub(v[1],v[5]), b2=csub(v[2],v[6]), b3=csub(v[3],v[7]);
    b1 = cpx{K8*(b1.x+b1.y), K8*(b1.y-b1.x)};   // * e^{-i pi/4}
    b2 = cpx{b2.y, -b2.x};                      // * -i
    b3 = cpx{K8*(b3.y-b3.x), -K8*(b3.x+b3.y)};  // * e^{-3i pi/4}
    cpx c0=cadd(a0,a2), c2=csub(a0,a2);
    cpx c1=cadd(a1,a3), c3=csub(a1,a3); c3 = cpx{c3.y, -c3.x};
    cpx d0=cadd(b0,b2), d2=csub(b0,b2);
    cpx d1=cadd(b1,b3), d3=csub(b1,b3); d3 = cpx{d3.y, -d3.x};
    v[0]=cadd(c0,c1); v[4]=csub(c0,c1);
    v[2]=cadd(c2,c3); v[6]=csub(c2,c3);
    v[1]=cadd(d0,d1); v[5]=csub(d0,d1);
    v[3]=cadd(d2,d3); v[7]=csub(d2,d3);
}

// Empirical champion (measured 56us dispatch / 76% VALUBusy / 57% occupancy):
// launch_bounds(256,4) -> 64 VGPR spill-free; XOR-swizzled LDS transposes;
// Cl via lane-rotate shuffle; Z-LDS Hermitian partner; FPW=4, 2048 blocks.
__global__ __launch_bounds__(256, 4) void phase_loss_kernel(
        const float* __restrict__ y, const float* __restrict__ g,
        float* __restrict__ acc, int* __restrict__ ticket,
        float* __restrict__ out, int T, int n_frames, float inv_count) {
    // XOR-swizzled transpose scratch: 512 float2/wave, no pad.
    // Stage-1: row k stored at lane^(72k)  (72k = k<<6 | k<<3, bit-disjoint with lane bits)
    // Stage-2: row k stored at lane^(65k)  (65k = k<<6 | k)
    __shared__ float2 xch_all[4][512];
    __shared__ float wsum[3][4];
    __shared__ int is_last;

    const int tid  = threadIdx.x;
    const int lane = tid & 63;
    const int wid  = tid >> 6;
    float2* xch = xch_all[wid];

    // Per-lane twiddles in registers, once per kernel.
    cpx tw1[8], tw2[8];
    #pragma unroll
    for (int k = 0; k < 8; ++k) {
        float a1 = -(2.0f * PI_F / 512.0f) * (float)(lane * k);
        __sincosf(a1, &tw1[k].y, &tw1[k].x);
        float a2 = -(2.0f * PI_F / 64.0f) * (float)((lane & 7) * k);
        __sincosf(a2, &tw2[k].y, &tw2[k].x);
    }

    float ip = 0.f, gd = 0.f, iaf = 0.f;
    cpx Cp[5];
    const int tmax_int = (T - 256) / HOP;   // frames [2, tmax_int] need no reflect
    const int ra1 = (lane >> 3) * 72 + (lane & 7);       // stage-1 read base, XOR (r<<3)
    const int ra2 = (lane >> 3) * 65 + (lane & 7) * 8;   // stage-2 read base, XOR r
    const int rsl = (lane + 63) & 63;                    // rotate-down-1 shuffle source

    auto do_frame = [&](int t, bool accum, bool hp) {
        cpx v[8];
        const int base = t * HOP - 256 + lane;
        if (t >= 2 && t <= tmax_int) {       // fast path: no reflect clamps
            #pragma unroll
            for (int r = 0; r < 8; ++r) {
                int j = base + r * 64;
                v[r].x = y[j]; v[r].y = g[j];
            }
        } else {
            #pragma unroll
            for (int r = 0; r < 8; ++r) {
                int j = base + r * 64;
                j = (j < 0) ? -j : j;
                j = (j >= T) ? (2 * T - 2 - j) : j;
                v[r].x = y[j]; v[r].y = g[j];
            }
        }
        // stage 1: DFT8 over n2, twiddle W512^{lane*k}
        dft8(v);
        #pragma unroll
        for (int k = 1; k < 8; ++k) v[k] = cmul(v[k], tw1[k]);
        LDS_FENCE();   // orders prev frame's Z reads vs these writes
        #pragma unroll
        for (int k = 0; k < 8; ++k)
            xch[lane ^ (72 * k)] = make_float2(v[k].x, v[k].y);
        LDS_FENCE();
        #pragma unroll
        for (int r = 0; r < 8; ++r) {
            float2 tmp = xch[ra1 ^ (r << 3)];
            v[r] = cpx{tmp.x, tmp.y};
        }
        // stage 2: DFT8, twiddle W64^{(lane&7)*k}
        dft8(v);
        #pragma unroll
        for (int k = 1; k < 8; ++k) v[k] = cmul(v[k], tw2[k]);
        LDS_FENCE();
        #pragma unroll
        for (int k = 0; k < 8; ++k)
            xch[lane ^ (65 * k)] = make_float2(v[k].x, v[k].y);
        LDS_FENCE();
        #pragma unroll
        for (int r = 0; r < 8; ++r) {
            float2 tmp = xch[ra2 ^ r];
            v[r] = cpx{tmp.x, tmp.y};
        }
        // stage 3: DFT8 -> bin f = lane + 64*reg, full spectrum in regs
        dft8(v);
        // write Z over the (dead) xch buffer; Hermitian partner = Z[(512-f)&511]
        float2* Z = xch;
        LDS_FENCE();
        #pragma unroll
        for (int j = 0; j < 8; ++j)
            Z[lane + (j << 6)] = make_float2(v[j].x, v[j].y);
        LDS_FENCE();
        cpx Cc[5];
        #pragma unroll
        for (int jj = 0; jj < 5; ++jj) {
            const int f = lane + (jj << 6);
            float2 tmp = Z[(512 - f) & 511];
            float ur = v[jj].x + tmp.x, ui = v[jj].y - tmp.y;   // 2*Y
            float vx = v[jj].x - tmp.x, vy = v[jj].y + tmp.y;   // 2i*G
            Cc[jj].x = fmaf(ur, vy, -ui * vx);                  // C = Y*conj(G), x4
            Cc[jj].y = fmaf(ur, vx,  ui * vy);
        }
        if (accum) {
            // cm[jj] = C[f-1] via lane-rotate shuffle:
            // rot[jj] = Cc[jj] from lane-1 (wraps: lane0 gets lane63 = bin 63+64jj);
            // lane0 must instead take rot[jj-1] (= bin 64jj-1). jj==0 lane0 garbage,
            // discarded (gd row-0 term == ip term). rprev after loop = C[255] @lane0.
            cpx rprev = {0.f, 0.f};
            #pragma unroll
            for (int jj = 0; jj < 4; ++jj) {
                cpx rj;
                rj.x = __shfl(Cc[jj].x, rsl, 64);
                rj.y = __shfl(Cc[jj].y, rsl, 64);
                cpx cmj = (jj > 0 && lane == 0) ? rprev : rj;
                cpx cc = Cc[jj];
                float aw = abs_angle(cc.x, cc.y);
                ip += aw;
                cpx qg = cmulc(cmj, cc);
                float gt = abs_angle(qg.x, qg.y);
                gd += (jj == 0 && lane == 0) ? aw : gt;   // gd row 0 term == ip term
                if (hp) {
                    cpx qi = cmulc(Cp[jj], cc);
                    iaf += abs_angle(qi.x, qi.y);
                } else {
                    iaf += aw;                             // iaf col 0 term == ip term
                }
                rprev = rj;
            }
            if (lane == 0) {   // bin 256
                cpx cc = Cc[4];
                float aw = abs_angle(cc.x, cc.y);
                ip += aw;
                cpx qg = cmulc(rprev, cc);                // rprev = C[255] at lane 0
                gd += abs_angle(qg.x, qg.y);
                if (hp) {
                    cpx qi = cmulc(Cp[4], cc);
                    iaf += abs_angle(qi.x, qi.y);
                } else {
                    iaf += aw;
                }
            }
        }
        #pragma unroll
        for (int jj = 0; jj < 5; ++jj) Cp[jj] = Cc[jj];
    };

    const int chain   = (blockIdx.x << 2) | wid;        // 0 .. 4*gridDim.x-1
    const int nchains = (int)(gridDim.x << 2);
    const int t0 = chain * FPW;
    int tend = t0 + FPW;
    if (chain == nchains - 1) tend = n_frames;          // last chain takes remainder
    const bool havep = (t0 > 0);

    if (havep) do_frame(t0 - 1, false, false);
    #pragma unroll 2
    for (int t = t0; t < tend; ++t)
        do_frame(t, true, havep || (t > t0));

    // block reduce
    __syncthreads();
    for (int off = 32; off; off >>= 1) {
        ip  += __shfl_down(ip, off);
        gd  += __shfl_down(gd, off);
        iaf += __shfl_down(iaf, off);
    }
    if (lane == 0) { wsum[0][wid] = ip; wsum[1][wid] = gd; wsum[2][wid] = iaf; }
    __syncthreads();
    if (tid == 0) {
        const int slot = (int)(blockIdx.x & (NSLOTS - 1));
        atomicAdd(acc + 0 * NSLOTS + slot, wsum[0][0] + wsum[0][1] + wsum[0][2] + wsum[0][3]);
        atomicAdd(acc + 1 * NSLOTS + slot, wsum[1][0] + wsum[1][1] + wsum[1][2] + wsum[1][3]);
        atomicAdd(acc + 2 * NSLOTS + slot, wsum[2][0] + wsum[2][1] + wsum[2][2] + wsum[2][3]);
        __threadfence();
        is_last = (atomicAdd(ticket, 1) == (int)gridDim.x - 1);
    }
    __syncthreads();
    if (is_last) {
        for (int l = 0; l < 3; l++) {
            float vv = __hip_atomic_load(acc + l * NSLOTS + tid,
                                         __ATOMIC_RELAXED, __HIP_MEMORY_SCOPE_AGENT);
            for (int off = 32; off; off >>= 1) vv += __shfl_down(vv, off);
            if (lane == 0) wsum[l][wid] = vv;
        }
        __syncthreads();
        if (tid < 3)
            out[tid] = (wsum[tid][0] + wsum[tid][1] + wsum[tid][2] + wsum[tid][3]) * inv_count;
    }
}

extern "C" void kernel_launch(void* const* d_in, const int* in_sizes, int n_in,
                              void* d_out, int out_size, void* d_ws, size_t ws_size,
                              hipStream_t stream) {
    const float* y = (const float*)d_in[0];
    const float* g = (const float*)d_in[1];
    float* out = (float*)d_out;
    float* acc = (float*)d_ws;
    int* ticket = (int*)((char*)d_ws + 3 * NSLOTS * sizeof(float));
    const int T = in_sizes[0];
    const int n_frames = T / HOP + 1;                  // 32769
    int n_blocks = n_frames / (FPW * 4);               // 2048 (last chain absorbs rest)
    if (n_blocks < 1) n_blocks = 1;

    hipMemsetAsync(d_ws, 0, 3 * NSLOTS * sizeof(float) + sizeof(int), stream);
    const float inv_count = 1.0f / (257.0f * (float)n_frames);
    phase_loss_kernel<<<n_blocks, 256, 0, stream>>>(y, g, acc, ticket, out,
                                                    T, n_frames, inv_count);
}

// Round 11
// 143.570 us; speedup vs baseline: 1.5946x; 1.5946x over previous
//
#include <hip/hip_runtime.h>
#include <math.h>

#define HOP     128
#define NSLOTS  256
#define FPW     4      // frames per wave-chain: 8192 chains / 2048 blocks = full residency
#define PI_F    3.14159265358979323846f
#define PI2_F   1.57079632679489661923f
#define K8      0.70710678118654752440f

// Zero-instruction ordering fence for intra-wave LDS cross-lane handoffs.
#define LDS_FENCE() do { __asm__ volatile("" ::: "memory"); \
                         __builtin_amdgcn_wave_barrier(); } while (0)

struct cpx { float x, y; };
__device__ __forceinline__ cpx cadd(cpx a, cpx b){ return {a.x+b.x, a.y+b.y}; }
__device__ __forceinline__ cpx csub(cpx a, cpx b){ return {a.x-b.x, a.y-b.y}; }
__device__ __forceinline__ cpx cmul(cpx a, cpx b){
    return {fmaf(a.x,b.x,-a.y*b.y), fmaf(a.x,b.y, a.y*b.x)};
}
__device__ __forceinline__ cpx cmulc(cpx a, cpx b){  // a*conj(b)
    return {fmaf(a.x,b.x, a.y*b.y), fmaf(a.y,b.x,-a.x*b.y)};
}

// |atan2(im,re)| in [0,pi]
__device__ __forceinline__ float abs_angle(float re, float im) {
    float a = fabsf(im), b = fabsf(re);
    float mn = fminf(a, b), mx = fmaxf(a, b);
    float t = __fdividef(mn, fmaxf(mx, 1e-37f));
    float t2 = t * t;
    float p = fmaf(t2, -0.0117212f, 0.05265332f);
    p = fmaf(t2, p, -0.11643287f);
    p = fmaf(t2, p, 0.19354346f);
    p = fmaf(t2, p, -0.33262347f);
    p = fmaf(t2, p, 0.99997726f);
    float r = t * p;
    r = (a > b) ? (PI2_F - r) : r;
    r = (re < 0.f) ? (PI_F - r) : r;
    return r;
}

// In-register 8-point DFT, natural-order output.
__device__ __forceinline__ void dft8(cpx v[8]) {
    cpx a0=cadd(v[0],v[4]), a1=cadd(v[1],v[5]), a2=cadd(v[2],v[6]), a3=cadd(v[3],v[7]);
    cpx b0=csub(v[0],v[4]), b1=csub(v[1],v[5]), b2=csub(v[2],v[6]), b3=csub(v[3],v[7]);
    b1 = cpx{K8*(b1.x+b1.y), K8*(b1.y-b1.x)};   // * e^{-i pi/4}
    b2 = cpx{b2.y, -b2.x};                      // * -i
    b3 = cpx{K8*(b3.y-b3.x), -K8*(b3.x+b3.y)};  // * e^{-3i pi/4}
    cpx c0=cadd(a0,a2), c2=csub(a0,a2);
    cpx c1=cadd(a1,a3), c3=csub(a1,a3); c3 = cpx{c3.y, -c3.x};
    cpx d0=cadd(b0,b2), d2=csub(b0,b2);
    cpx d1=cadd(b1,b3), d3=csub(b1,b3); d3 = cpx{d3.y, -d3.x};
    v[0]=cadd(c0,c1); v[4]=csub(c0,c1);
    v[2]=cadd(c2,c3); v[6]=csub(c2,c3);
    v[1]=cadd(d0,d1); v[5]=csub(d0,d1);
    v[3]=cadd(d2,d3); v[7]=csub(d2,d3);
}

// Spill-proof register budget (survives BOTH observed toolchain moods):
//  - tw1 (14 regs) in VGPRs: critical path every frame, fits with margin.
//  - tw2 in LDS (7 broadcast ds_read_b64/frame): saves 14 regs.
//  - Hermitian partner via shuffle, no Z LDS round-trip.
// Peak live ~58 < 64 -> no allocator mood spills (r2/r10 lesson: the 32-reg
// twiddle version spills to 82MB scratch under the SGPR=64 toolchain).
__global__ __launch_bounds__(256, 4) void phase_loss_kernel(
        const float* __restrict__ y, const float* __restrict__ g,
        float* __restrict__ acc, int* __restrict__ ticket,
        float* __restrict__ out, int T, int n_frames, float inv_count) {
    __shared__ float2 xch_all[4][512];   // XOR-swizzled transpose scratch (per wave)
    __shared__ float2 tw2_tab[7][8];     // W64^{(lane&7)*k}, k=1..7 (broadcast reads)
    __shared__ float wsum[3][4];
    __shared__ int is_last;

    const int tid  = threadIdx.x;
    const int lane = tid & 63;
    const int wid  = tid >> 6;
    const int l8   = lane & 7;
    float2* xch = xch_all[wid];

    // tw2 table once per block (same __sincosf expressions -> bit-identical).
    if (tid < 56) {
        const int k = (tid >> 3) + 1, l = tid & 7;
        float s, c;
        __sincosf(-(2.0f * PI_F / 64.0f) * (float)(l * k), &s, &c);
        tw2_tab[tid >> 3][l] = make_float2(c, s);
    }
    __syncthreads();

    // Stage-1 twiddles in registers (14 VGPRs), once per kernel.
    cpx tw1[7];
    #pragma unroll
    for (int k = 1; k < 8; ++k) {
        float a1 = -(2.0f * PI_F / 512.0f) * (float)(lane * k);
        __sincosf(a1, &tw1[k - 1].y, &tw1[k - 1].x);
    }

    float ip = 0.f, gd = 0.f, iaf = 0.f;
    cpx Cp[5];
    const int tmax_int = (T - 256) / HOP;   // frames [2, tmax_int] need no reflect
    const int ra1 = (lane >> 3) * 72 + (lane & 7);       // stage-1 read base, XOR (r<<3)
    const int ra2 = (lane >> 3) * 65 + (lane & 7) * 8;   // stage-2 read base, XOR r
    const int rsl = (lane + 63) & 63;                    // rotate-down-1 shuffle source
    const int rsh = (64 - lane) & 63;                    // Hermitian partner source lane

    auto do_frame = [&](int t, bool accum, bool hp) {
        cpx v[8];
        const int base = t * HOP - 256 + lane;
        if (t >= 2 && t <= tmax_int) {       // fast path: no reflect clamps
            #pragma unroll
            for (int r = 0; r < 8; ++r) {
                int j = base + r * 64;
                v[r].x = y[j]; v[r].y = g[j];
            }
        } else {
            #pragma unroll
            for (int r = 0; r < 8; ++r) {
                int j = base + r * 64;
                j = (j < 0) ? -j : j;
                j = (j >= T) ? (2 * T - 2 - j) : j;
                v[r].x = y[j]; v[r].y = g[j];
            }
        }
        // stage 1: DFT8 over n2, twiddle W512^{lane*k} (registers)
        dft8(v);
        #pragma unroll
        for (int k = 1; k < 8; ++k) v[k] = cmul(v[k], tw1[k - 1]);
        LDS_FENCE();   // orders prev frame's stage-2 reads vs these writes
        #pragma unroll
        for (int k = 0; k < 8; ++k)
            xch[lane ^ (72 * k)] = make_float2(v[k].x, v[k].y);
        LDS_FENCE();
        #pragma unroll
        for (int r = 0; r < 8; ++r) {
            float2 tmp = xch[ra1 ^ (r << 3)];
            v[r] = cpx{tmp.x, tmp.y};
        }
        // stage 2: DFT8, twiddle W64^{(lane&7)*k} from LDS table (broadcast)
        dft8(v);
        #pragma unroll
        for (int k = 1; k < 8; ++k) {
            float2 tw = tw2_tab[k - 1][l8];
            v[k] = cmul(v[k], cpx{tw.x, tw.y});
        }
        LDS_FENCE();
        #pragma unroll
        for (int k = 0; k < 8; ++k)
            xch[lane ^ (65 * k)] = make_float2(v[k].x, v[k].y);
        LDS_FENCE();
        #pragma unroll
        for (int r = 0; r < 8; ++r) {
            float2 tmp = xch[ra2 ^ r];
            v[r] = cpx{tmp.x, tmp.y};
        }
        // stage 3: DFT8 -> bin f = lane + 64*reg, full spectrum in regs
        dft8(v);
        // Hermitian partner Z[(512-f)&511] via shuffle, no LDS round-trip:
        // lane>=1: partner = v[7-jj] from lane 64-lane; lane==0: own v[(8-jj)&7].
        cpx Cc[5];
        #pragma unroll
        for (int jj = 0; jj < 5; ++jj) {
            float px = __shfl(v[7 - jj].x, rsh, 64);
            float py = __shfl(v[7 - jj].y, rsh, 64);
            px = (lane == 0) ? v[(8 - jj) & 7].x : px;
            py = (lane == 0) ? v[(8 - jj) & 7].y : py;
            float ur = v[jj].x + px, ui = v[jj].y - py;   // 2*Y
            float vx = v[jj].x - px, vy = v[jj].y + py;   // 2i*G
            Cc[jj].x = fmaf(ur, vy, -ui * vx);            // C = Y*conj(G), x4
            Cc[jj].y = fmaf(ur, vx,  ui * vy);
        }
        if (accum) {
            // C[f-1] via lane-rotate shuffle; lane0 patched from previous jj.
            cpx rprev = {0.f, 0.f};
            #pragma unroll
            for (int jj = 0; jj < 4; ++jj) {
                cpx rj;
                rj.x = __shfl(Cc[jj].x, rsl, 64);
                rj.y = __shfl(Cc[jj].y, rsl, 64);
                cpx cmj = (jj > 0 && lane == 0) ? rprev : rj;
                cpx cc = Cc[jj];
                float aw = abs_angle(cc.x, cc.y);
                ip += aw;
                cpx qg = cmulc(cmj, cc);
                float gt = abs_angle(qg.x, qg.y);
                gd += (jj == 0 && lane == 0) ? aw : gt;   // gd row 0 term == ip term
                if (hp) {
                    cpx qi = cmulc(Cp[jj], cc);
                    iaf += abs_angle(qi.x, qi.y);
                } else {
                    iaf += aw;                             // iaf col 0 term == ip term
                }
                rprev = rj;
            }
            if (lane == 0) {   // bin 256
                cpx cc = Cc[4];
                float aw = abs_angle(cc.x, cc.y);
                ip += aw;
                cpx qg = cmulc(rprev, cc);                // rprev = C[255] at lane 0
                gd += abs_angle(qg.x, qg.y);
                if (hp) {
                    cpx qi = cmulc(Cp[4], cc);
                    iaf += abs_angle(qi.x, qi.y);
                } else {
                    iaf += aw;
                }
            }
        }
        #pragma unroll
        for (int jj = 0; jj < 5; ++jj) Cp[jj] = Cc[jj];
    };

    const int chain   = (blockIdx.x << 2) | wid;        // 0 .. 4*gridDim.x-1
    const int nchains = (int)(gridDim.x << 2);
    const int t0 = chain * FPW;
    int tend = t0 + FPW;
    if (chain == nchains - 1) tend = n_frames;          // last chain takes remainder
    const bool havep = (t0 > 0);

    if (havep) do_frame(t0 - 1, false, false);
    #pragma unroll 2
    for (int t = t0; t < tend; ++t)
        do_frame(t, true, havep || (t > t0));

    // block reduce
    __syncthreads();
    for (int off = 32; off; off >>= 1) {
        ip  += __shfl_down(ip, off);
        gd  += __shfl_down(gd, off);
        iaf += __shfl_down(iaf, off);
    }
    if (lane == 0) { wsum[0][wid] = ip; wsum[1][wid] = gd; wsum[2][wid] = iaf; }
    __syncthreads();
    if (tid == 0) {
        const int slot = (int)(blockIdx.x & (NSLOTS - 1));
        atomicAdd(acc + 0 * NSLOTS + slot, wsum[0][0] + wsum[0][1] + wsum[0][2] + wsum[0][3]);
        atomicAdd(acc + 1 * NSLOTS + slot, wsum[1][0] + wsum[1][1] + wsum[1][2] + wsum[1][3]);
        atomicAdd(acc + 2 * NSLOTS + slot, wsum[2][0] + wsum[2][1] + wsum[2][2] + wsum[2][3]);
        __threadfence();
        is_last = (atomicAdd(ticket, 1) == (int)gridDim.x - 1);
    }
    __syncthreads();
    if (is_last) {
        for (int l = 0; l < 3; l++) {
            float vv = __hip_atomic_load(acc + l * NSLOTS + tid,
                                         __ATOMIC_RELAXED, __HIP_MEMORY_SCOPE_AGENT);
            for (int off = 32; off; off >>= 1) vv += __shfl_down(vv, off);
            if (lane == 0) wsum[l][wid] = vv;
        }
        __syncthreads();
        if (tid < 3)
            out[tid] = (wsum[tid][0] + wsum[tid][1] + wsum[tid][2] + wsum[tid][3]) * inv_count;
    }
}

extern "C" void kernel_launch(void* const* d_in, const int* in_sizes, int n_in,
                              void* d_out, int out_size, void* d_ws, size_t ws_size,
                              hipStream_t stream) {
    const float* y = (const float*)d_in[0];
    const float* g = (const float*)d_in[1];
    float* out = (float*)d_out;
    float* acc = (float*)d_ws;
    int* ticket = (int*)((char*)d_ws + 3 * NSLOTS * sizeof(float));
    const int T = in_sizes[0];
    const int n_frames = T / HOP + 1;                  // 32769
    int n_blocks = n_frames / (FPW * 4);               // 2048 (last chain absorbs rest)
    if (n_blocks < 1) n_blocks = 1;

    hipMemsetAsync(d_ws, 0, 3 * NSLOTS * sizeof(float) + sizeof(int), stream);
    const float inv_count = 1.0f / (257.0f * (float)n_frames);
    phase_loss_kernel<<<n_blocks, 256, 0, stream>>>(y, g, acc, ticket, out,
                                                    T, n_frames, inv_count);
}

// Round 12
// 141.290 us; speedup vs baseline: 1.6203x; 1.0161x over previous
//
#include <hip/hip_runtime.h>
#include <math.h>

#define HOP     128
#define NSLOTS  256
#define FPW     4      // frames per wave-chain: 8192 chains / 2048 blocks = full residency
#define PI_F    3.14159265358979323846f
#define PI2_F   1.57079632679489661923f
#define TWO_PI_F 6.28318530717958647692f
#define K8      0.70710678118654752440f

// Zero-instruction ordering fence for intra-wave LDS cross-lane handoffs.
#define LDS_FENCE() do { __asm__ volatile("" ::: "memory"); \
                         __builtin_amdgcn_wave_barrier(); } while (0)

struct cpx { float x, y; };
__device__ __forceinline__ cpx cadd(cpx a, cpx b){ return {a.x+b.x, a.y+b.y}; }
__device__ __forceinline__ cpx csub(cpx a, cpx b){ return {a.x-b.x, a.y-b.y}; }
__device__ __forceinline__ cpx cmul(cpx a, cpx b){
    return {fmaf(a.x,b.x,-a.y*b.y), fmaf(a.x,b.y, a.y*b.x)};
}

// signed atan2(im,re) in (-pi, pi] — same poly as the accepted abs_angle,
// with the sign folded in via copysign. One call per bin replaces the old
// THREE abs_angle calls + two cmulcs: ip=|th|, gd/iaf=|wrap(th_a - th_b)|
// (angle(a*conj(b)) == wrap(theta_a - theta_b), exact in real arithmetic).
__device__ __forceinline__ float sangle(float re, float im) {
    float a = fabsf(im), b = fabsf(re);
    float mn = fminf(a, b), mx = fmaxf(a, b);
    float t = __fdividef(mn, fmaxf(mx, 1e-37f));
    float t2 = t * t;
    float p = fmaf(t2, -0.0117212f, 0.05265332f);
    p = fmaf(t2, p, -0.11643287f);
    p = fmaf(t2, p, 0.19354346f);
    p = fmaf(t2, p, -0.33262347f);
    p = fmaf(t2, p, 0.99997726f);
    float r = t * p;
    r = (a > b) ? (PI2_F - r) : r;
    r = (re < 0.f) ? (PI_F - r) : r;
    return copysignf(r, im);
}

// |wrap(d)| for d in (-2pi, 2pi): one conditional 2pi correction each side.
__device__ __forceinline__ float abs_wrap(float d) {
    d = (d >  PI_F) ? d - TWO_PI_F : d;
    d = (d < -PI_F) ? d + TWO_PI_F : d;
    return fabsf(d);
}

// In-register 8-point DFT, natural-order output.
__device__ __forceinline__ void dft8(cpx v[8]) {
    cpx a0=cadd(v[0],v[4]), a1=cadd(v[1],v[5]), a2=cadd(v[2],v[6]), a3=cadd(v[3],v[7]);
    cpx b0=csub(v[0],v[4]), b1=csub(v[1],v[5]), b2=csub(v[2],v[6]), b3=csub(v[3],v[7]);
    b1 = cpx{K8*(b1.x+b1.y), K8*(b1.y-b1.x)};   // * e^{-i pi/4}
    b2 = cpx{b2.y, -b2.x};                      // * -i
    b3 = cpx{K8*(b3.y-b3.x), -K8*(b3.x+b3.y)};  // * e^{-3i pi/4}
    cpx c0=cadd(a0,a2), c2=csub(a0,a2);
    cpx c1=cadd(a1,a3), c3=csub(a1,a3); c3 = cpx{c3.y, -c3.x};
    cpx d0=cadd(b0,b2), d2=csub(b0,b2);
    cpx d1=cadd(b1,b3), d3=csub(b1,b3); d3 = cpx{d3.y, -d3.x};
    v[0]=cadd(c0,c1); v[4]=csub(c0,c1);
    v[2]=cadd(c2,c3); v[6]=csub(c2,c3);
    v[1]=cadd(d0,d1); v[5]=csub(d0,d1);
    v[3]=cadd(d2,d3); v[7]=csub(d2,d3);
}

// Spill-proof register budget (survives BOTH observed toolchain moods):
// tw1 (14 regs) in VGPRs; tw2 in LDS broadcast; Hermitian partner via shuffle;
// per-bin state reduced to ONE float (signed phase) instead of a cpx.
// Peak live ~50 < 64 with margin.
__global__ __launch_bounds__(256, 4) void phase_loss_kernel(
        const float* __restrict__ y, const float* __restrict__ g,
        float* __restrict__ acc, int* __restrict__ ticket,
        float* __restrict__ out, int T, int n_frames, float inv_count) {
    __shared__ float2 xch_all[4][512];   // XOR-swizzled transpose scratch (per wave)
    __shared__ float2 tw2_tab[7][8];     // W64^{(lane&7)*k}, k=1..7 (broadcast reads)
    __shared__ float wsum[3][4];
    __shared__ int is_last;

    const int tid  = threadIdx.x;
    const int lane = tid & 63;
    const int wid  = tid >> 6;
    const int l8   = lane & 7;
    float2* xch = xch_all[wid];

    // tw2 table once per block (same __sincosf expressions -> bit-identical).
    if (tid < 56) {
        const int k = (tid >> 3) + 1, l = tid & 7;
        float s, c;
        __sincosf(-(2.0f * PI_F / 64.0f) * (float)(l * k), &s, &c);
        tw2_tab[tid >> 3][l] = make_float2(c, s);
    }
    __syncthreads();

    // Stage-1 twiddles in registers (14 VGPRs), once per kernel.
    cpx tw1[7];
    #pragma unroll
    for (int k = 1; k < 8; ++k) {
        float a1 = -(2.0f * PI_F / 512.0f) * (float)(lane * k);
        __sincosf(a1, &tw1[k - 1].y, &tw1[k - 1].x);
    }

    float ip = 0.f, gd = 0.f, iaf = 0.f;
    float thp[5];                           // previous frame's signed phases
    #pragma unroll
    for (int jj = 0; jj < 5; ++jj) thp[jj] = 0.f;

    const int tmax_int = (T - 256) / HOP;   // frames [2, tmax_int] need no reflect
    const int ra1 = (lane >> 3) * 72 + (lane & 7);       // stage-1 read base, XOR (r<<3)
    const int ra2 = (lane >> 3) * 65 + (lane & 7) * 8;   // stage-2 read base, XOR r
    const int rsl = (lane + 63) & 63;                    // rotate-down-1 shuffle source
    const int rsh = (64 - lane) & 63;                    // Hermitian partner source lane

    auto do_frame = [&](int t, bool accum, bool hp) {
        cpx v[8];
        const int base = t * HOP - 256 + lane;
        if (t >= 2 && t <= tmax_int) {       // fast path: no reflect clamps
            #pragma unroll
            for (int r = 0; r < 8; ++r) {
                int j = base + r * 64;
                v[r].x = y[j]; v[r].y = g[j];
            }
        } else {
            #pragma unroll
            for (int r = 0; r < 8; ++r) {
                int j = base + r * 64;
                j = (j < 0) ? -j : j;
                j = (j >= T) ? (2 * T - 2 - j) : j;
                v[r].x = y[j]; v[r].y = g[j];
            }
        }
        // stage 1: DFT8 over n2, twiddle W512^{lane*k} (registers)
        dft8(v);
        #pragma unroll
        for (int k = 1; k < 8; ++k) v[k] = cmul(v[k], tw1[k - 1]);
        LDS_FENCE();   // orders prev frame's stage-2 reads vs these writes
        #pragma unroll
        for (int k = 0; k < 8; ++k)
            xch[lane ^ (72 * k)] = make_float2(v[k].x, v[k].y);
        LDS_FENCE();
        #pragma unroll
        for (int r = 0; r < 8; ++r) {
            float2 tmp = xch[ra1 ^ (r << 3)];
            v[r] = cpx{tmp.x, tmp.y};
        }
        // stage 2: DFT8, twiddle W64^{(lane&7)*k} from LDS table (broadcast)
        dft8(v);
        #pragma unroll
        for (int k = 1; k < 8; ++k) {
            float2 tw = tw2_tab[k - 1][l8];
            v[k] = cmul(v[k], cpx{tw.x, tw.y});
        }
        LDS_FENCE();
        #pragma unroll
        for (int k = 0; k < 8; ++k)
            xch[lane ^ (65 * k)] = make_float2(v[k].x, v[k].y);
        LDS_FENCE();
        #pragma unroll
        for (int r = 0; r < 8; ++r) {
            float2 tmp = xch[ra2 ^ r];
            v[r] = cpx{tmp.x, tmp.y};
        }
        // stage 3: DFT8 -> bin f = lane + 64*reg, full spectrum in regs
        dft8(v);
        // Hermitian partner via shuffle (lane>=1: v[7-jj] from lane 64-lane;
        // lane==0: own v[(8-jj)&7]) -> C = Y*conj(G) (x4) -> signed phase.
        float th[5];
        #pragma unroll
        for (int jj = 0; jj < 5; ++jj) {
            float px = __shfl(v[7 - jj].x, rsh, 64);
            float py = __shfl(v[7 - jj].y, rsh, 64);
            px = (lane == 0) ? v[(8 - jj) & 7].x : px;
            py = (lane == 0) ? v[(8 - jj) & 7].y : py;
            float ur = v[jj].x + px, ui = v[jj].y - py;   // 2*Y
            float vx = v[jj].x - px, vy = v[jj].y + py;   // 2i*G
            float ccx = fmaf(ur, vy, -ui * vx);           // C = Y*conj(G), x4
            float ccy = fmaf(ur, vx,  ui * vy);
            th[jj] = sangle(ccx, ccy);                    // phi = angle(C)
        }
        if (accum) {
            // phi[f-1] via lane-rotate shuffle of ONE float; lane0 patched from
            // previous jj. jj==0 lane0 garbage, discarded (gd row-0 == ip term).
            float rprev = 0.f;
            #pragma unroll
            for (int jj = 0; jj < 4; ++jj) {
                float rj = __shfl(th[jj], rsl, 64);
                float thm = (jj > 0 && lane == 0) ? rprev : rj;
                float aw = fabsf(th[jj]);
                ip += aw;
                float gt = abs_wrap(thm - th[jj]);
                gd += (jj == 0 && lane == 0) ? aw : gt;   // gd row 0 term == ip term
                iaf += hp ? abs_wrap(thp[jj] - th[jj]) : aw;  // iaf col 0 == ip term
                rprev = rj;
            }
            if (lane == 0) {   // bin 256
                float aw = fabsf(th[4]);
                ip += aw;
                gd += abs_wrap(rprev - th[4]);            // rprev = phi[255] at lane 0
                iaf += hp ? abs_wrap(thp[4] - th[4]) : aw;
            }
        }
        #pragma unroll
        for (int jj = 0; jj < 5; ++jj) thp[jj] = th[jj];
    };

    const int chain   = (blockIdx.x << 2) | wid;        // 0 .. 4*gridDim.x-1
    const int nchains = (int)(gridDim.x << 2);
    const int t0 = chain * FPW;
    int tend = t0 + FPW;
    if (chain == nchains - 1) tend = n_frames;          // last chain takes remainder
    const bool havep = (t0 > 0);

    if (havep) do_frame(t0 - 1, false, false);
    #pragma unroll 2
    for (int t = t0; t < tend; ++t)
        do_frame(t, true, havep || (t > t0));

    // block reduce
    __syncthreads();
    for (int off = 32; off; off >>= 1) {
        ip  += __shfl_down(ip, off);
        gd  += __shfl_down(gd, off);
        iaf += __shfl_down(iaf, off);
    }
    if (lane == 0) { wsum[0][wid] = ip; wsum[1][wid] = gd; wsum[2][wid] = iaf; }
    __syncthreads();
    if (tid == 0) {
        const int slot = (int)(blockIdx.x & (NSLOTS - 1));
        atomicAdd(acc + 0 * NSLOTS + slot, wsum[0][0] + wsum[0][1] + wsum[0][2] + wsum[0][3]);
        atomicAdd(acc + 1 * NSLOTS + slot, wsum[1][0] + wsum[1][1] + wsum[1][2] + wsum[1][3]);
        atomicAdd(acc + 2 * NSLOTS + slot, wsum[2][0] + wsum[2][1] + wsum[2][2] + wsum[2][3]);
        __threadfence();
        is_last = (atomicAdd(ticket, 1) == (int)gridDim.x - 1);
    }
    __syncthreads();
    if (is_last) {
        for (int l = 0; l < 3; l++) {
            float vv = __hip_atomic_load(acc + l * NSLOTS + tid,
                                         __ATOMIC_RELAXED, __HIP_MEMORY_SCOPE_AGENT);
            for (int off = 32; off; off >>= 1) vv += __shfl_down(vv, off);
            if (lane == 0) wsum[l][wid] = vv;
        }
        __syncthreads();
        if (tid < 3)
            out[tid] = (wsum[tid][0] + wsum[tid][1] + wsum[tid][2] + wsum[tid][3]) * inv_count;
    }
}

extern "C" void kernel_launch(void* const* d_in, const int* in_sizes, int n_in,
                              void* d_out, int out_size, void* d_ws, size_t ws_size,
                              hipStream_t stream) {
    const float* y = (const float*)d_in[0];
    const float* g = (const float*)d_in[1];
    float* out = (float*)d_out;
    float* acc = (float*)d_ws;
    int* ticket = (int*)((char*)d_ws + 3 * NSLOTS * sizeof(float));
    const int T = in_sizes[0];
    const int n_frames = T / HOP + 1;                  // 32769
    int n_blocks = n_frames / (FPW * 4);               // 2048 (last chain absorbs rest)
    if (n_blocks < 1) n_blocks = 1;

    hipMemsetAsync(d_ws, 0, 3 * NSLOTS * sizeof(float) + sizeof(int), stream);
    const float inv_count = 1.0f / (257.0f * (float)n_frames);
    phase_loss_kernel<<<n_blocks, 256, 0, stream>>>(y, g, acc, ticket, out,
                                                    T, n_frames, inv_count);
}

// Round 13
// 138.751 us; speedup vs baseline: 1.6499x; 1.0183x over previous
//
#include <hip/hip_runtime.h>
#include <math.h>

#define HOP     128
#define NSLOTS  256
#define FPW     4      // frames per wave-chain: 8192 chains / 2048 blocks
#define PI_F    3.14159265358979323846f
#define PI2_F   1.57079632679489661923f
#define TWO_PI_F 6.28318530717958647692f
#define K8      0.70710678118654752440f

// Zero-instruction ordering fence for intra-wave LDS cross-lane handoffs.
#define LDS_FENCE() do { __asm__ volatile("" ::: "memory"); \
                         __builtin_amdgcn_wave_barrier(); } while (0)

struct cpx { float x, y; };
__device__ __forceinline__ cpx cadd(cpx a, cpx b){ return {a.x+b.x, a.y+b.y}; }
__device__ __forceinline__ cpx csub(cpx a, cpx b){ return {a.x-b.x, a.y-b.y}; }
__device__ __forceinline__ cpx cmul(cpx a, cpx b){
    return {fmaf(a.x,b.x,-a.y*b.y), fmaf(a.x,b.y, a.y*b.x)};
}

// signed atan2(im,re) in (-pi, pi] — same poly as the accepted abs_angle.
// ONE call per bin: ip=|th|, gd/iaf=|wrap(th_a - th_b)| (r12, absmax 0.0).
__device__ __forceinline__ float sangle(float re, float im) {
    float a = fabsf(im), b = fabsf(re);
    float mn = fminf(a, b), mx = fmaxf(a, b);
    float t = __fdividef(mn, fmaxf(mx, 1e-37f));
    float t2 = t * t;
    float p = fmaf(t2, -0.0117212f, 0.05265332f);
    p = fmaf(t2, p, -0.11643287f);
    p = fmaf(t2, p, 0.19354346f);
    p = fmaf(t2, p, -0.33262347f);
    p = fmaf(t2, p, 0.99997726f);
    float r = t * p;
    r = (a > b) ? (PI2_F - r) : r;
    r = (re < 0.f) ? (PI_F - r) : r;
    return copysignf(r, im);
}

// |wrap(d)| for d in (-2pi, 2pi).
__device__ __forceinline__ float abs_wrap(float d) {
    d = (d >  PI_F) ? d - TWO_PI_F : d;
    d = (d < -PI_F) ? d + TWO_PI_F : d;
    return fabsf(d);
}

// In-register 8-point DFT, natural-order output.
__device__ __forceinline__ void dft8(cpx v[8]) {
    cpx a0=cadd(v[0],v[4]), a1=cadd(v[1],v[5]), a2=cadd(v[2],v[6]), a3=cadd(v[3],v[7]);
    cpx b0=csub(v[0],v[4]), b1=csub(v[1],v[5]), b2=csub(v[2],v[6]), b3=csub(v[3],v[7]);
    b1 = cpx{K8*(b1.x+b1.y), K8*(b1.y-b1.x)};   // * e^{-i pi/4}
    b2 = cpx{b2.y, -b2.x};                      // * -i
    b3 = cpx{K8*(b3.y-b3.x), -K8*(b3.x+b3.y)};  // * e^{-3i pi/4}
    cpx c0=cadd(a0,a2), c2=csub(a0,a2);
    cpx c1=cadd(a1,a3), c3=csub(a1,a3); c3 = cpx{c3.y, -c3.x};
    cpx d0=cadd(b0,b2), d2=csub(b0,b2);
    cpx d1=cadd(b1,b3), d3=csub(b1,b3); d3 = cpx{d3.y, -d3.x};
    v[0]=cadd(c0,c1); v[4]=csub(c0,c1);
    v[2]=cadd(c2,c3); v[6]=csub(c2,c3);
    v[1]=cadd(d0,d1); v[5]=csub(d0,d1);
    v[3]=cadd(d2,d3); v[7]=csub(d2,d3);
}

// Frame-parity LDS double-buffer: frame t uses xch[t&1], so the cross-frame
// WAR hazard (this frame's stage-1 writes vs prev frame's stage-2 reads)
// vanishes -> 3 fences/frame instead of 4, and the compiler can overlap a
// frame's loads+dft8 with the previous frame's LDS tail.
// Spill-proof budget (r10/r11 lesson): tw1 in VGPRs (14), tw2 in LDS
// broadcast, shuffle Hermitian, ONE float of per-bin state. Peak live ~50.
__global__ __launch_bounds__(256, 4) void phase_loss_kernel(
        const float* __restrict__ y, const float* __restrict__ g,
        float* __restrict__ acc, int* __restrict__ ticket,
        float* __restrict__ out, int T, int n_frames, float inv_count) {
    __shared__ float2 xch_all[4][2][512]; // per wave, per frame-parity
    __shared__ float2 tw2_tab[7][8];      // W64^{(lane&7)*k}, k=1..7 (broadcast)
    __shared__ float wsum[3][4];
    __shared__ int is_last;

    const int tid  = threadIdx.x;
    const int lane = tid & 63;
    const int wid  = tid >> 6;
    const int l8   = lane & 7;

    // tw2 table once per block (same __sincosf expressions -> bit-identical).
    if (tid < 56) {
        const int k = (tid >> 3) + 1, l = tid & 7;
        float s, c;
        __sincosf(-(2.0f * PI_F / 64.0f) * (float)(l * k), &s, &c);
        tw2_tab[tid >> 3][l] = make_float2(c, s);
    }
    __syncthreads();

    // Stage-1 twiddles in registers (14 VGPRs), once per kernel.
    cpx tw1[7];
    #pragma unroll
    for (int k = 1; k < 8; ++k) {
        float a1 = -(2.0f * PI_F / 512.0f) * (float)(lane * k);
        __sincosf(a1, &tw1[k - 1].y, &tw1[k - 1].x);
    }

    float ip = 0.f, gd = 0.f, iaf = 0.f;
    float thp[5];                           // previous frame's signed phases
    #pragma unroll
    for (int jj = 0; jj < 5; ++jj) thp[jj] = 0.f;

    const int tmax_int = (T - 256) / HOP;   // frames [2, tmax_int] need no reflect
    const int ra1 = (lane >> 3) * 72 + (lane & 7);       // stage-1 read base, XOR (r<<3)
    const int ra2 = (lane >> 3) * 65 + (lane & 7) * 8;   // stage-2 read base, XOR r
    const int rsl = (lane + 63) & 63;                    // rotate-down-1 shuffle source
    const int rsh = (64 - lane) & 63;                    // Hermitian partner source lane

    auto do_frame = [&](int t, bool accum, bool hp) {
        float2* xch = xch_all[wid][t & 1];   // frame-parity buffer
        cpx v[8];
        const int base = t * HOP - 256 + lane;
        if (t >= 2 && t <= tmax_int) {       // fast path: no reflect clamps
            #pragma unroll
            for (int r = 0; r < 8; ++r) {
                int j = base + r * 64;
                v[r].x = y[j]; v[r].y = g[j];
            }
        } else {
            #pragma unroll
            for (int r = 0; r < 8; ++r) {
                int j = base + r * 64;
                j = (j < 0) ? -j : j;
                j = (j >= T) ? (2 * T - 2 - j) : j;
                v[r].x = y[j]; v[r].y = g[j];
            }
        }
        // stage 1: DFT8 over n2, twiddle W512^{lane*k} (registers).
        // No leading fence: this buffer was last touched 2 frames ago, with
        // 3+ fences in between (ordering holds transitively).
        dft8(v);
        #pragma unroll
        for (int k = 1; k < 8; ++k) v[k] = cmul(v[k], tw1[k - 1]);
        #pragma unroll
        for (int k = 0; k < 8; ++k)
            xch[lane ^ (72 * k)] = make_float2(v[k].x, v[k].y);
        LDS_FENCE();
        #pragma unroll
        for (int r = 0; r < 8; ++r) {
            float2 tmp = xch[ra1 ^ (r << 3)];
            v[r] = cpx{tmp.x, tmp.y};
        }
        // stage 2: DFT8, twiddle W64^{(lane&7)*k} from LDS table (broadcast)
        dft8(v);
        #pragma unroll
        for (int k = 1; k < 8; ++k) {
            float2 tw = tw2_tab[k - 1][l8];
            v[k] = cmul(v[k], cpx{tw.x, tw.y});
        }
        LDS_FENCE();   // intra-frame WAR: stage-2 writes overwrite stage-1 slots
        #pragma unroll
        for (int k = 0; k < 8; ++k)
            xch[lane ^ (65 * k)] = make_float2(v[k].x, v[k].y);
        LDS_FENCE();
        #pragma unroll
        for (int r = 0; r < 8; ++r) {
            float2 tmp = xch[ra2 ^ r];
            v[r] = cpx{tmp.x, tmp.y};
        }
        // stage 3: DFT8 -> bin f = lane + 64*reg, full spectrum in regs
        dft8(v);
        // Hermitian partner via shuffle -> C = Y*conj(G) (x4) -> signed phase.
        float th[5];
        #pragma unroll
        for (int jj = 0; jj < 5; ++jj) {
            float px = __shfl(v[7 - jj].x, rsh, 64);
            float py = __shfl(v[7 - jj].y, rsh, 64);
            px = (lane == 0) ? v[(8 - jj) & 7].x : px;
            py = (lane == 0) ? v[(8 - jj) & 7].y : py;
            float ur = v[jj].x + px, ui = v[jj].y - py;   // 2*Y
            float vx = v[jj].x - px, vy = v[jj].y + py;   // 2i*G
            float ccx = fmaf(ur, vy, -ui * vx);           // C = Y*conj(G), x4
            float ccy = fmaf(ur, vx,  ui * vy);
            th[jj] = sangle(ccx, ccy);                    // phi = angle(C)
        }
        if (accum) {
            // phi[f-1] via lane-rotate shuffle; lane0 patched from previous jj.
            float rprev = 0.f;
            #pragma unroll
            for (int jj = 0; jj < 4; ++jj) {
                float rj = __shfl(th[jj], rsl, 64);
                float thm = (jj > 0 && lane == 0) ? rprev : rj;
                float aw = fabsf(th[jj]);
                ip += aw;
                float gt = abs_wrap(thm - th[jj]);
                gd += (jj == 0 && lane == 0) ? aw : gt;   // gd row 0 term == ip term
                iaf += hp ? abs_wrap(thp[jj] - th[jj]) : aw;  // iaf col 0 == ip term
                rprev = rj;
            }
            if (lane == 0) {   // bin 256
                float aw = fabsf(th[4]);
                ip += aw;
                gd += abs_wrap(rprev - th[4]);            // rprev = phi[255] at lane 0
                iaf += hp ? abs_wrap(thp[4] - th[4]) : aw;
            }
        }
        #pragma unroll
        for (int jj = 0; jj < 5; ++jj) thp[jj] = th[jj];
    };

    const int chain   = (blockIdx.x << 2) | wid;        // 0 .. 4*gridDim.x-1
    const int nchains = (int)(gridDim.x << 2);
    const int t0 = chain * FPW;
    int tend = t0 + FPW;
    if (chain == nchains - 1) tend = n_frames;          // last chain takes remainder
    const bool havep = (t0 > 0);

    if (havep) do_frame(t0 - 1, false, false);
    #pragma unroll 2
    for (int t = t0; t < tend; ++t)
        do_frame(t, true, havep || (t > t0));

    // block reduce
    __syncthreads();
    for (int off = 32; off; off >>= 1) {
        ip  += __shfl_down(ip, off);
        gd  += __shfl_down(gd, off);
        iaf += __shfl_down(iaf, off);
    }
    if (lane == 0) { wsum[0][wid] = ip; wsum[1][wid] = gd; wsum[2][wid] = iaf; }
    __syncthreads();
    if (tid == 0) {
        const int slot = (int)(blockIdx.x & (NSLOTS - 1));
        atomicAdd(acc + 0 * NSLOTS + slot, wsum[0][0] + wsum[0][1] + wsum[0][2] + wsum[0][3]);
        atomicAdd(acc + 1 * NSLOTS + slot, wsum[1][0] + wsum[1][1] + wsum[1][2] + wsum[1][3]);
        atomicAdd(acc + 2 * NSLOTS + slot, wsum[2][0] + wsum[2][1] + wsum[2][2] + wsum[2][3]);
        __threadfence();
        is_last = (atomicAdd(ticket, 1) == (int)gridDim.x - 1);
    }
    __syncthreads();
    if (is_last) {
        for (int l = 0; l < 3; l++) {
            float vv = __hip_atomic_load(acc + l * NSLOTS + tid,
                                         __ATOMIC_RELAXED, __HIP_MEMORY_SCOPE_AGENT);
            for (int off = 32; off; off >>= 1) vv += __shfl_down(vv, off);
            if (lane == 0) wsum[l][wid] = vv;
        }
        __syncthreads();
        if (tid < 3)
            out[tid] = (wsum[tid][0] + wsum[tid][1] + wsum[tid][2] + wsum[tid][3]) * inv_count;
    }
}

extern "C" void kernel_launch(void* const* d_in, const int* in_sizes, int n_in,
                              void* d_out, int out_size, void* d_ws, size_t ws_size,
                              hipStream_t stream) {
    const float* y = (const float*)d_in[0];
    const float* g = (const float*)d_in[1];
    float* out = (float*)d_out;
    float* acc = (float*)d_ws;
    int* ticket = (int*)((char*)d_ws + 3 * NSLOTS * sizeof(float));
    const int T = in_sizes[0];
    const int n_frames = T / HOP + 1;                  // 32769
    int n_blocks = n_frames / (FPW * 4);               // 2048 (last chain absorbs rest)
    if (n_blocks < 1) n_blocks = 1;

    hipMemsetAsync(d_ws, 0, 3 * NSLOTS * sizeof(float) + sizeof(int), stream);
    const float inv_count = 1.0f / (257.0f * (float)n_frames);
    phase_loss_kernel<<<n_blocks, 256, 0, stream>>>(y, g, acc, ticket, out,
                                                    T, n_frames, inv_count);
}